// Round 9
// baseline (375.903 us; speedup 1.0000x reference)
//
#include <hip/hip_runtime.h>
#include <stdint.h>

using f4v = __attribute__((ext_vector_type(4))) float;
using s8v = __attribute__((ext_vector_type(8))) short;

constexpr int C_ = 128, H_ = 128, W_ = 128, HW_ = H_ * W_;
constexpr int S_ = 4;             // y-splits for k_dw
constexpr int OROWS = H_ / S_;    // 32 output rows per block
constexpr int CHB = 4;            // channels per k_dw block (wave-uniform)
constexpr int TPB = 512;
static_assert(OROWS == 32, "bias table indexing assumes 32 rows/block");

__device__ __forceinline__ unsigned f2bf(float f) {
  union { float f; unsigned u; } v; v.f = f;
  return (v.u + 0x7FFFu + ((v.u >> 16) & 1u)) >> 16;   // RTNE
}

// force a wave-uniform float into an SGPR
__device__ __forceinline__ float sgpr(float v) {
  return __int_as_float(__builtin_amdgcn_readfirstlane(__float_as_int(v)));
}

// ---------------------------------------------------------------------------
// Kernel 1: fused depthwise branches -> add (bf16). Compute BIT-IDENTICAL to
// the verified round-5 kernel (116 us full-batch, VGPR 40, zero spill).
// Round-9 instrumentation: batch-offset n0 so it launches as TWO half-batch
// grids (~58 us each) — pushes k_mix (single launch) to the top of the
// rocprof table so its counters finally become visible. Each half-grid is
// 1024 blocks = exactly 4/CU x 256 CU: one full residency wave, no tail
// change. ws layout [n][g=c/4][px][c%4] bf16, 8-B px-granules.
// ---------------------------------------------------------------------------
__global__ __launch_bounds__(TPB) void k_dw(
    const float* __restrict__ x,
    const float* __restrict__ w0,  const float* __restrict__ b0,
    const float* __restrict__ w01, const float* __restrict__ b01,
    const float* __restrict__ w02, const float* __restrict__ b02,
    const float* __restrict__ w11, const float* __restrict__ b11,
    const float* __restrict__ w12, const float* __restrict__ b12,
    unsigned short* __restrict__ ws, int n0)
{
  __shared__ float xs[CHB][16][144];          // 128 px at cols 8..135; pads = 0
  __shared__ unsigned short ebuf[16][CHB][128];
  __shared__ float bias_row[CHB][OROWS];

  const int t = threadIdx.x;
  const int yb = blockIdx.x, g = blockIdx.y, n = blockIdx.z + n0;
  const int ch = t >> 7, xl = t & 127;        // ch uniform per wave
  const int c0 = g * CHB, c = c0 + ch;

  const int obase = yb * OROWS;
  const int oend  = obase + OROWS;
  const int sbase = (obase >= 5) ? (obase - 5) : 0;
  const int lastrow = (oend + 4 <= H_ - 1) ? (oend + 4) : (H_ - 1);
  const int nrows = lastrow - sbase + 1;      // 37 (edge) or 42 (middle)
  const int nchunk = (nrows + 15) >> 4;

  // wave-uniform weights -> SGPRs (41 scalars)
  float w0t[9], w01t[5], w02t[5], w11t[11], w12t[11];
#pragma unroll
  for (int k = 0; k < 9; ++k)  w0t[k] = sgpr(w0[c * 9 + k]);
#pragma unroll
  for (int k = 0; k < 5; ++k)  { w01t[k] = sgpr(w01[c * 5 + k]); w02t[k] = sgpr(w02[c * 5 + k]); }
#pragma unroll
  for (int k = 0; k < 11; ++k) { w11t[k] = sgpr(w11[c * 11 + k]); w12t[k] = sgpr(w12[c * 11 + k]); }

  // boundary-bias table: 4 ch x 32 outputs
  if (t < CHB * OROWS) {
    const int cb = t >> 5, oo = t & 31;
    const int y = obase + oo, cc = c0 + cb;
    float s5 = 0.f, s11 = 0.f;
#pragma unroll
    for (int k = 0; k < 5; ++k)  if ((unsigned)(y - 2 + k) < 128u) s5  += w02[cc * 5 + k];
#pragma unroll
    for (int k = 0; k < 11; ++k) if ((unsigned)(y - 5 + k) < 128u) s11 += w12[cc * 11 + k];
    bias_row[cb][oo] = b0[cc] + b02[cc] + b12[cc] + b01[cc] * s5 + b11[cc] * s11;
  }

  // zero the halo pad columns once
  if (t < 256) {
    const int zc = t >> 6, zr = (t >> 2) & 15, zq = t & 3;
    const int col = (zq < 2) ? zq * 4 : 136 + (zq - 2) * 4;
    *(float4*)&xs[zc][zr][col] = make_float4(0.f, 0.f, 0.f, 0.f);
  }

  float acc[16];
#pragma unroll
  for (int i = 0; i < 16; ++i) acc[i] = 0.f;

  unsigned short* wsp = ws + (size_t)(n * 32 + g) * HW_ * 4;

  for (int cidx = 0; cidx < nchunk; ++cidx) {
    const int r0g = sbase + cidx * 16;
    const int rem_rows = nrows - cidx * 16;
    const int rlim = rem_rows < 16 ? rem_rows : 16;
    __syncthreads();
#pragma unroll
    for (int i = 0; i < 4; ++i) {
      const int id = i * TPB + t;
      const int chs = id >> 9;
      const int rs  = (id >> 5) & 15;
      const int c4  = id & 31;
      float4 v = make_float4(0.f, 0.f, 0.f, 0.f);
      if (rs < rlim)
        v = *(const float4*)(x + (size_t)((n * C_ + c0 + chs) * H_ + r0g + rs) * W_ + c4 * 4);
      *(float4*)&xs[chs][rs][8 + c4 * 4] = v;
    }
    __syncthreads();
#pragma unroll
    for (int rr = 0; rr < 16; ++rr) {
      if (rr < rlim) {
        float win[11];
#pragma unroll
        for (int k = 0; k < 11; ++k) win[k] = xs[ch][rr][xl + 3 + k];
        float h11 = w11t[0] * win[0];
#pragma unroll
        for (int k = 1; k < 11; ++k) h11 += w11t[k] * win[k];
        float h5 = w01t[0] * win[3];
#pragma unroll
        for (int k = 1; k < 5; ++k) h5 += w01t[k] * win[3 + k];
        float r0v = w0t[0] * win[4] + w0t[1] * win[5] + w0t[2] * win[6];
        float r1v = w0t[3] * win[4] + w0t[4] * win[5] + w0t[5] * win[6];
        float r2v = w0t[6] * win[4] + w0t[7] * win[5] + w0t[8] * win[6];
#pragma unroll
        for (int tt = 0; tt < 11; ++tt) acc[(rr + 5 - tt) & 15] += w12t[tt] * h11;
#pragma unroll
        for (int tt = 0; tt < 5; ++tt)  acc[(rr + 2 - tt) & 15] += w02t[tt] * h5;
        acc[(rr + 1) & 15]  += r0v;
        acc[rr & 15]        += r1v;
        acc[(rr + 15) & 15] += r2v;
        const int o_e = r0g + rr - 5;
        const int slot = (rr + 11) & 15;
        if (o_e >= obase)
          ebuf[rr][ch][xl] = (unsigned short)f2bf(acc[slot] + bias_row[ch][o_e - obase]);
        acc[slot] = 0.f;
      }
    }
    __syncthreads();
    for (int id = t; id < 2048; id += TPB) {
      const int orr = id >> 7, px = id & 127;
      const int o = r0g + orr - 5;
      if (orr < rlim && o >= obase) {
        uint2 pk;
        pk.x = ebuf[orr][0][px] | ((unsigned)ebuf[orr][1][px] << 16);
        pk.y = ebuf[orr][2][px] | ((unsigned)ebuf[orr][3][px] << 16);
        *(uint2*)(wsp + ((size_t)o * W_ + px) * 4) = pk;
      }
    }
  }
  if (oend == H_) {
    __syncthreads();
#pragma unroll
    for (int orr = 0; orr < 5; ++orr) {
      const int o = H_ - 5 + orr;
      const int slot = (o - sbase) & 15;
      ebuf[orr][ch][xl] = (unsigned short)f2bf(acc[slot] + bias_row[ch][o - obase]);
    }
    __syncthreads();
    for (int id = t; id < 640; id += TPB) {
      const int orr = id >> 7, px = id & 127;
      const int o = H_ - 5 + orr;
      uint2 pk;
      pk.x = ebuf[orr][0][px] | ((unsigned)ebuf[orr][1][px] << 16);
      pk.y = ebuf[orr][2][px] | ((unsigned)ebuf[orr][3][px] << 16);
      *(uint2*)(wsp + ((size_t)o * W_ + px) * 4) = pk;
    }
  }
}

// ---------------------------------------------------------------------------
// Kernel 2: 1x1 channel mix via MFMA. BIT-IDENTICAL compute to the round-5
// verified version, launched ONCE over the full batch (n0=0, g2.y=16).
// With k_dw split into ~58 us halves, this kernel's dispatches must top the
// rocprof table (traffic floor alone is ~53 us) -> first real counters.
// ---------------------------------------------------------------------------
constexpr int PXB = 64;

__global__ __launch_bounds__(256) void k_mix(
    const float* __restrict__ x,
    const float* __restrict__ w3, const float* __restrict__ b3,
    const unsigned short* __restrict__ ws,
    float* __restrict__ out, int n0)
{
  const int t = threadIdx.x;
  const int wv = t >> 6, lane = t & 63, q = lane >> 4, lp = lane & 15;
  const int n = blockIdx.y + n0;
  const int px0 = blockIdx.x * PXB;

  // A fragments: rows o = 32*wv + 16*m + lp, k-slice ks*32 + q*8 (bf16-packed)
  s8v A[2][4];
  float b3v[2][4];
#pragma unroll
  for (int m = 0; m < 2; ++m) {
    const int o = 32 * wv + 16 * m + lp;
#pragma unroll
    for (int ks = 0; ks < 4; ++ks) {
      const float* src = w3 + o * 128 + ks * 32 + q * 8;
      float4 f0 = *(const float4*)src;
      float4 f1 = *(const float4*)(src + 4);
      union { s8v v; unsigned u[4]; } pk;
      pk.u[0] = f2bf(f0.x) | (f2bf(f0.y) << 16);
      pk.u[1] = f2bf(f0.z) | (f2bf(f0.w) << 16);
      pk.u[2] = f2bf(f1.x) | (f2bf(f1.y) << 16);
      pk.u[3] = f2bf(f1.z) | (f2bf(f1.w) << 16);
      A[m][ks] = pk.v;
    }
#pragma unroll
    for (int r = 0; r < 4; ++r) b3v[m][r] = b3[32 * wv + 16 * m + 4 * q + r];
  }

  const unsigned short* wsn = ws + (size_t)n * 32 * HW_ * 4;

#pragma unroll
  for (int npg = 0; npg < PXB / 16; ++npg) {
    const int pp = px0 + npg * 16 + lp;
    s8v B[4];
#pragma unroll
    for (int ks = 0; ks < 4; ++ks) {
      const int gg8 = ks * 4 + q;            // 8-ch group for k = ks*32+q*8
      const unsigned short* gsrc = wsn + ((size_t)(gg8 * 2) * HW_ + pp) * 4;
      union { s8v v; uint2 u2[2]; } pk;
      pk.u2[0] = *(const uint2*)gsrc;                    // ch 8*gg8+0..3
      pk.u2[1] = *(const uint2*)(gsrc + (size_t)HW_ * 4);// ch 8*gg8+4..7
      B[ks] = pk.v;
    }
    // hoist the x (residual-multiply) loads so they overlap the MFMA chain
    float xv[2][4];
#pragma unroll
    for (int m = 0; m < 2; ++m)
#pragma unroll
      for (int r = 0; r < 4; ++r) {
        const int o = 32 * wv + 16 * m + 4 * q + r;
        xv[m][r] = x[((size_t)(n * C_ + o) << 14) + pp];
      }
    f4v acc[2] = {{0.f,0.f,0.f,0.f},{0.f,0.f,0.f,0.f}};
#pragma unroll
    for (int ks = 0; ks < 4; ++ks) {
#pragma unroll
      for (int m = 0; m < 2; ++m)
        acc[m] = __builtin_amdgcn_mfma_f32_16x16x32_bf16(A[m][ks], B[ks], acc[m], 0, 0, 0);
    }
#pragma unroll
    for (int m = 0; m < 2; ++m)
#pragma unroll
      for (int r = 0; r < 4; ++r) {
        const int o = 32 * wv + 16 * m + 4 * q + r;   // D row = q*4+r
        const size_t idx = ((size_t)(n * C_ + o) << 14) + pp;
        out[idx] = (acc[m][r] + b3v[m][r]) * xv[m][r];
      }
  }
}

extern "C" void kernel_launch(void* const* d_in, const int* in_sizes, int n_in,
                              void* d_out, int out_size, void* d_ws, size_t ws_size,
                              hipStream_t stream) {
  const float* x   = (const float*)d_in[0];
  const float* w0  = (const float*)d_in[1];
  const float* b0  = (const float*)d_in[2];
  const float* w01 = (const float*)d_in[3];
  const float* b01 = (const float*)d_in[4];
  const float* w02 = (const float*)d_in[5];
  const float* b02 = (const float*)d_in[6];
  const float* w11 = (const float*)d_in[7];
  const float* b11 = (const float*)d_in[8];
  const float* w12 = (const float*)d_in[9];
  const float* b12 = (const float*)d_in[10];
  const float* w3  = (const float*)d_in[11];
  const float* b3  = (const float*)d_in[12];
  unsigned short* ws = (unsigned short*)d_ws;   // 16*32*16384*4*2 = 64 MiB
  float* out = (float*)d_out;

  dim3 g1(S_, 32, 8);        // (y-splits, 4-ch groups, half-batch) x 2 launches
  k_dw<<<g1, TPB, 0, stream>>>(x, w0, b0, w01, b01, w02, b02, w11, b11, w12, b12, ws, 0);
  k_dw<<<g1, TPB, 0, stream>>>(x, w0, b0, w01, b01, w02, b02, w11, b11, w12, b12, ws, 8);

  dim3 g2(HW_ / PXB, 16);    // (64-px blocks, full batch) single launch
  k_mix<<<g2, 256, 0, stream>>>(x, w3, b3, ws, out, 0);
}

// Round 10
// 358.780 us; speedup vs baseline: 1.0477x; 1.0477x over previous
//
#include <hip/hip_runtime.h>
#include <stdint.h>

using f4v = __attribute__((ext_vector_type(4))) float;
using s8v = __attribute__((ext_vector_type(8))) short;

constexpr int C_ = 128, H_ = 128, W_ = 128, HW_ = H_ * W_;
constexpr int S_ = 4;             // y-splits for k_dw
constexpr int OROWS = H_ / S_;    // 32 output rows per block
constexpr int CHB = 4;            // channels per k_dw block (wave-uniform)
constexpr int TPB = 512;
static_assert(OROWS == 32, "bias table indexing assumes 32 rows/block");

__device__ __forceinline__ unsigned f2bf(float f) {
  union { float f; unsigned u; } v; v.f = f;
  return (v.u + 0x7FFFu + ((v.u >> 16) & 1u)) >> 16;   // RTNE
}

// force a wave-uniform float into an SGPR
__device__ __forceinline__ float sgpr(float v) {
  return __int_as_float(__builtin_amdgcn_readfirstlane(__float_as_int(v)));
}

// ---------------------------------------------------------------------------
// Kernel 1: fused depthwise branches -> add (bf16). BIT-IDENTICAL to the
// verified round-5 kernel (116 us, VGPR 40, WRITE == ws payload, no spill).
// Single full-batch launch (round-9's half-split was instrumentation only).
// ws layout [n][g=c/4][px][c%4] bf16, 8-B px-granules.
// ---------------------------------------------------------------------------
__global__ __launch_bounds__(TPB) void k_dw(
    const float* __restrict__ x,
    const float* __restrict__ w0,  const float* __restrict__ b0,
    const float* __restrict__ w01, const float* __restrict__ b01,
    const float* __restrict__ w02, const float* __restrict__ b02,
    const float* __restrict__ w11, const float* __restrict__ b11,
    const float* __restrict__ w12, const float* __restrict__ b12,
    unsigned short* __restrict__ ws)
{
  __shared__ float xs[CHB][16][144];          // 128 px at cols 8..135; pads = 0
  __shared__ unsigned short ebuf[16][CHB][128];
  __shared__ float bias_row[CHB][OROWS];

  const int t = threadIdx.x;
  const int yb = blockIdx.x, g = blockIdx.y, n = blockIdx.z;
  const int ch = t >> 7, xl = t & 127;        // ch uniform per wave
  const int c0 = g * CHB, c = c0 + ch;

  const int obase = yb * OROWS;
  const int oend  = obase + OROWS;
  const int sbase = (obase >= 5) ? (obase - 5) : 0;
  const int lastrow = (oend + 4 <= H_ - 1) ? (oend + 4) : (H_ - 1);
  const int nrows = lastrow - sbase + 1;      // 37 (edge) or 42 (middle)
  const int nchunk = (nrows + 15) >> 4;

  // wave-uniform weights -> SGPRs (41 scalars)
  float w0t[9], w01t[5], w02t[5], w11t[11], w12t[11];
#pragma unroll
  for (int k = 0; k < 9; ++k)  w0t[k] = sgpr(w0[c * 9 + k]);
#pragma unroll
  for (int k = 0; k < 5; ++k)  { w01t[k] = sgpr(w01[c * 5 + k]); w02t[k] = sgpr(w02[c * 5 + k]); }
#pragma unroll
  for (int k = 0; k < 11; ++k) { w11t[k] = sgpr(w11[c * 11 + k]); w12t[k] = sgpr(w12[c * 11 + k]); }

  // boundary-bias table: 4 ch x 32 outputs
  if (t < CHB * OROWS) {
    const int cb = t >> 5, oo = t & 31;
    const int y = obase + oo, cc = c0 + cb;
    float s5 = 0.f, s11 = 0.f;
#pragma unroll
    for (int k = 0; k < 5; ++k)  if ((unsigned)(y - 2 + k) < 128u) s5  += w02[cc * 5 + k];
#pragma unroll
    for (int k = 0; k < 11; ++k) if ((unsigned)(y - 5 + k) < 128u) s11 += w12[cc * 11 + k];
    bias_row[cb][oo] = b0[cc] + b02[cc] + b12[cc] + b01[cc] * s5 + b11[cc] * s11;
  }

  // zero the halo pad columns once
  if (t < 256) {
    const int zc = t >> 6, zr = (t >> 2) & 15, zq = t & 3;
    const int col = (zq < 2) ? zq * 4 : 136 + (zq - 2) * 4;
    *(float4*)&xs[zc][zr][col] = make_float4(0.f, 0.f, 0.f, 0.f);
  }

  float acc[16];
#pragma unroll
  for (int i = 0; i < 16; ++i) acc[i] = 0.f;

  unsigned short* wsp = ws + (size_t)(n * 32 + g) * HW_ * 4;

  for (int cidx = 0; cidx < nchunk; ++cidx) {
    const int r0g = sbase + cidx * 16;
    const int rem_rows = nrows - cidx * 16;
    const int rlim = rem_rows < 16 ? rem_rows : 16;
    __syncthreads();
#pragma unroll
    for (int i = 0; i < 4; ++i) {
      const int id = i * TPB + t;
      const int chs = id >> 9;
      const int rs  = (id >> 5) & 15;
      const int c4  = id & 31;
      float4 v = make_float4(0.f, 0.f, 0.f, 0.f);
      if (rs < rlim)
        v = *(const float4*)(x + (size_t)((n * C_ + c0 + chs) * H_ + r0g + rs) * W_ + c4 * 4);
      *(float4*)&xs[chs][rs][8 + c4 * 4] = v;
    }
    __syncthreads();
#pragma unroll
    for (int rr = 0; rr < 16; ++rr) {
      if (rr < rlim) {
        float win[11];
#pragma unroll
        for (int k = 0; k < 11; ++k) win[k] = xs[ch][rr][xl + 3 + k];
        float h11 = w11t[0] * win[0];
#pragma unroll
        for (int k = 1; k < 11; ++k) h11 += w11t[k] * win[k];
        float h5 = w01t[0] * win[3];
#pragma unroll
        for (int k = 1; k < 5; ++k) h5 += w01t[k] * win[3 + k];
        float r0v = w0t[0] * win[4] + w0t[1] * win[5] + w0t[2] * win[6];
        float r1v = w0t[3] * win[4] + w0t[4] * win[5] + w0t[5] * win[6];
        float r2v = w0t[6] * win[4] + w0t[7] * win[5] + w0t[8] * win[6];
#pragma unroll
        for (int tt = 0; tt < 11; ++tt) acc[(rr + 5 - tt) & 15] += w12t[tt] * h11;
#pragma unroll
        for (int tt = 0; tt < 5; ++tt)  acc[(rr + 2 - tt) & 15] += w02t[tt] * h5;
        acc[(rr + 1) & 15]  += r0v;
        acc[rr & 15]        += r1v;
        acc[(rr + 15) & 15] += r2v;
        const int o_e = r0g + rr - 5;
        const int slot = (rr + 11) & 15;
        if (o_e >= obase)
          ebuf[rr][ch][xl] = (unsigned short)f2bf(acc[slot] + bias_row[ch][o_e - obase]);
        acc[slot] = 0.f;
      }
    }
    __syncthreads();
    for (int id = t; id < 2048; id += TPB) {
      const int orr = id >> 7, px = id & 127;
      const int o = r0g + orr - 5;
      if (orr < rlim && o >= obase) {
        uint2 pk;
        pk.x = ebuf[orr][0][px] | ((unsigned)ebuf[orr][1][px] << 16);
        pk.y = ebuf[orr][2][px] | ((unsigned)ebuf[orr][3][px] << 16);
        *(uint2*)(wsp + ((size_t)o * W_ + px) * 4) = pk;
      }
    }
  }
  if (oend == H_) {
    __syncthreads();
#pragma unroll
    for (int orr = 0; orr < 5; ++orr) {
      const int o = H_ - 5 + orr;
      const int slot = (o - sbase) & 15;
      ebuf[orr][ch][xl] = (unsigned short)f2bf(acc[slot] + bias_row[ch][o - obase]);
    }
    __syncthreads();
    for (int id = t; id < 640; id += TPB) {
      const int orr = id >> 7, px = id & 127;
      const int o = H_ - 5 + orr;
      uint2 pk;
      pk.x = ebuf[orr][0][px] | ((unsigned)ebuf[orr][1][px] << 16);
      pk.y = ebuf[orr][2][px] | ((unsigned)ebuf[orr][3][px] << 16);
      *(uint2*)(wsp + ((size_t)o * W_ + px) * 4) = pk;
    }
  }
}

// ---------------------------------------------------------------------------
// Kernel 2: 1x1 channel mix via MFMA. Round-10: SINGLE-WAVE BLOCKS.
// Identical computation to the verified round-5/9 kernel; the former in-block
// wave index wv becomes blockIdx.y (waves were already fully independent:
// no LDS, disjoint output channels, shared-nothing). 16384 one-wave blocks
// give the scheduler 4x finer packing: counters showed 2 resident 4-wave
// blocks/CU (Occupancy 25%) with ALL pipes idle -> latency-bound; VGPR 84
// permits ~5-6 waves/SIMD, so single-wave blocks should triple residency.
// ---------------------------------------------------------------------------
constexpr int PXB = 64;

__global__ __launch_bounds__(64) void k_mix(
    const float* __restrict__ x,
    const float* __restrict__ w3, const float* __restrict__ b3,
    const unsigned short* __restrict__ ws,
    float* __restrict__ out)
{
  const int t = threadIdx.x;
  const int wv = blockIdx.y;                 // was t>>6: out-ch group [32wv, 32wv+32)
  const int lane = t & 63, q = lane >> 4, lp = lane & 15;
  const int n = blockIdx.z;
  const int px0 = blockIdx.x * PXB;

  // A fragments: rows o = 32*wv + 16*m + lp, k-slice ks*32 + q*8 (bf16-packed)
  s8v A[2][4];
  float b3v[2][4];
#pragma unroll
  for (int m = 0; m < 2; ++m) {
    const int o = 32 * wv + 16 * m + lp;
#pragma unroll
    for (int ks = 0; ks < 4; ++ks) {
      const float* src = w3 + o * 128 + ks * 32 + q * 8;
      float4 f0 = *(const float4*)src;
      float4 f1 = *(const float4*)(src + 4);
      union { s8v v; unsigned u[4]; } pk;
      pk.u[0] = f2bf(f0.x) | (f2bf(f0.y) << 16);
      pk.u[1] = f2bf(f0.z) | (f2bf(f0.w) << 16);
      pk.u[2] = f2bf(f1.x) | (f2bf(f1.y) << 16);
      pk.u[3] = f2bf(f1.z) | (f2bf(f1.w) << 16);
      A[m][ks] = pk.v;
    }
#pragma unroll
    for (int r = 0; r < 4; ++r) b3v[m][r] = b3[32 * wv + 16 * m + 4 * q + r];
  }

  const unsigned short* wsn = ws + (size_t)n * 32 * HW_ * 4;

#pragma unroll
  for (int npg = 0; npg < PXB / 16; ++npg) {
    const int pp = px0 + npg * 16 + lp;
    s8v B[4];
#pragma unroll
    for (int ks = 0; ks < 4; ++ks) {
      const int gg8 = ks * 4 + q;            // 8-ch group for k = ks*32+q*8
      const unsigned short* gsrc = wsn + ((size_t)(gg8 * 2) * HW_ + pp) * 4;
      union { s8v v; uint2 u2[2]; } pk;
      pk.u2[0] = *(const uint2*)gsrc;                    // ch 8*gg8+0..3
      pk.u2[1] = *(const uint2*)(gsrc + (size_t)HW_ * 4);// ch 8*gg8+4..7
      B[ks] = pk.v;
    }
    // hoist the x (residual-multiply) loads so they overlap the MFMA chain
    float xv[2][4];
#pragma unroll
    for (int m = 0; m < 2; ++m)
#pragma unroll
      for (int r = 0; r < 4; ++r) {
        const int o = 32 * wv + 16 * m + 4 * q + r;
        xv[m][r] = x[((size_t)(n * C_ + o) << 14) + pp];
      }
    f4v acc[2] = {{0.f,0.f,0.f,0.f},{0.f,0.f,0.f,0.f}};
#pragma unroll
    for (int ks = 0; ks < 4; ++ks) {
#pragma unroll
      for (int m = 0; m < 2; ++m)
        acc[m] = __builtin_amdgcn_mfma_f32_16x16x32_bf16(A[m][ks], B[ks], acc[m], 0, 0, 0);
    }
#pragma unroll
    for (int m = 0; m < 2; ++m)
#pragma unroll
      for (int r = 0; r < 4; ++r) {
        const int o = 32 * wv + 16 * m + 4 * q + r;   // D row = q*4+r
        const size_t idx = ((size_t)(n * C_ + o) << 14) + pp;
        out[idx] = (acc[m][r] + b3v[m][r]) * xv[m][r];
      }
  }
}

extern "C" void kernel_launch(void* const* d_in, const int* in_sizes, int n_in,
                              void* d_out, int out_size, void* d_ws, size_t ws_size,
                              hipStream_t stream) {
  const float* x   = (const float*)d_in[0];
  const float* w0  = (const float*)d_in[1];
  const float* b0  = (const float*)d_in[2];
  const float* w01 = (const float*)d_in[3];
  const float* b01 = (const float*)d_in[4];
  const float* w02 = (const float*)d_in[5];
  const float* b02 = (const float*)d_in[6];
  const float* w11 = (const float*)d_in[7];
  const float* b11 = (const float*)d_in[8];
  const float* w12 = (const float*)d_in[9];
  const float* b12 = (const float*)d_in[10];
  const float* w3  = (const float*)d_in[11];
  const float* b3  = (const float*)d_in[12];
  unsigned short* ws = (unsigned short*)d_ws;   // 16*32*16384*4*2 = 64 MiB
  float* out = (float*)d_out;

  dim3 g1(S_, 32, 16);       // (y-splits, 4-ch groups, batch)
  k_dw<<<g1, TPB, 0, stream>>>(x, w0, b0, w01, b01, w02, b02, w11, b11, w12, b12, ws);

  dim3 g2(HW_ / PXB, 4, 16); // (64-px blocks, out-ch groups, batch) — 1 wave/block
  k_mix<<<g2, 64, 0, stream>>>(x, w3, b3, ws, out);
}